// Round 12
// baseline (394.267 us; speedup 1.0000x reference)
//
#include <hip/hip_runtime.h>

#define TB 2
#define TT 4096
#define TC 2048
#define TM 8192          // B*T
#define THD 64
#define TNCH 64          // chunks per batch

typedef __attribute__((ext_vector_type(8))) short bf16x8;
typedef __attribute__((ext_vector_type(4))) float f32x4;

__device__ __forceinline__ float us2f(unsigned short u){
    union { unsigned int u; float f; } x; x.u = ((unsigned int)u) << 16; return x.f;
}
__device__ __forceinline__ unsigned short f2us(float f){
    unsigned int u = __float_as_uint(f);
    unsigned int r = (u + 0x7fffu + ((u >> 16) & 1u)) >> 16;   // RNE bf16
    return (unsigned short)r;
}

// ---------------- generic fp32 -> bf16 convert ----------------
__global__ void k_cvt(const float* __restrict__ src, unsigned short* __restrict__ dst, int n4){
    int i = blockIdx.x * 256 + threadIdx.x;
    if (i < n4){
        float4 v = *(const float4*)(src + (size_t)i * 4);
        ushort4 u; u.x = f2us(v.x); u.y = f2us(v.y); u.z = f2us(v.z); u.w = f2us(v.w);
        *(ushort4*)(dst + (size_t)i * 4) = u;
    }
}

// ---------------- w1 [2048][160] f32 -> w1T [160][2048] bf16 ----------------
// grid 32 (ktiles of 64), 256 thr
__global__ void k_w1t(const float* __restrict__ w1, unsigned short* __restrict__ w1T){
    __shared__ float T[64][164];
    int tid = threadIdx.x;
    int k0 = blockIdx.x * 64;
    for (int i = tid; i < 2560; i += 256){   // 64 k x 40 float4-groups
        int kk = i / 40, g = i % 40;
        float4 v = *(const float4*)(w1 + (size_t)(k0 + kk) * 160 + g * 4);
        T[kk][g * 4 + 0] = v.x; T[kk][g * 4 + 1] = v.y;
        T[kk][g * 4 + 2] = v.z; T[kk][g * 4 + 3] = v.w;
    }
    __syncthreads();
    for (int i = tid; i < 2560; i += 256){   // 160 n x 16 groups (4 k each)
        int n = i >> 4, g = i & 15;
        ushort4 u;
        u.x = f2us(T[g * 4 + 0][n]); u.y = f2us(T[g * 4 + 1][n]);
        u.z = f2us(T[g * 4 + 2][n]); u.w = f2us(T[g * 4 + 3][n]);
        *(ushort4*)(w1T + (size_t)n * TC + k0 + g * 4) = u;
    }
}

// ---------------- w2 [5][32][2048] f32 -> w2T [5][2048][32] bf16 ----------------
// grid (32 ctiles, 5 f), 256 thr
__global__ void k_w2t(const float* __restrict__ w2, unsigned short* __restrict__ w2T){
    __shared__ float T[32][65];
    int tid = threadIdx.x;
    int f = blockIdx.y, c0 = blockIdx.x * 64;
#pragma unroll
    for (int i = 0; i < 2; ++i){
        int idx = i * 256 + tid;          // 512 float4 groups: 32 d x 16 g
        int d = idx >> 4, g = idx & 15;
        float4 v = *(const float4*)(w2 + ((size_t)f * 32 + d) * TC + c0 + g * 4);
        T[d][g * 4 + 0] = v.x; T[d][g * 4 + 1] = v.y;
        T[d][g * 4 + 2] = v.z; T[d][g * 4 + 3] = v.w;
    }
    __syncthreads();
    int cc = tid >> 2, g = tid & 3;       // 64 c x 4 groups(of 8 d)
    unsigned short* dst = w2T + ((size_t)f * TC + c0 + cc) * 32 + g * 8;
    ushort4 u0, u1;
    u0.x = f2us(T[g * 8 + 0][cc]); u0.y = f2us(T[g * 8 + 1][cc]);
    u0.z = f2us(T[g * 8 + 2][cc]); u0.w = f2us(T[g * 8 + 3][cc]);
    u1.x = f2us(T[g * 8 + 4][cc]); u1.y = f2us(T[g * 8 + 5][cc]);
    u1.z = f2us(T[g * 8 + 6][cc]); u1.w = f2us(T[g * 8 + 7][cc]);
    *(ushort4*)dst = u0; *(ushort4*)(dst + 4) = u1;
}

// ---------------- {Wr,Wk,Wv,Wg,dw1}[2048][64] f32 -> Wblk[mat][32 kb][64 h][64 kk] bf16 ----------------
// grid (32 ctiles, 5 mats), 256 thr
__global__ void k_cvt5t(const float* __restrict__ s0, const float* __restrict__ s1,
                        const float* __restrict__ s2, const float* __restrict__ s3,
                        const float* __restrict__ s4, unsigned short* __restrict__ Wblk){
    __shared__ float T[64][65];
    int tid = threadIdx.x;
    int mat = blockIdx.y, c0 = blockIdx.x * 64;    // c0 = kb*64
    const float* s = (mat == 0) ? s0 : (mat == 1) ? s1 : (mat == 2) ? s2 : (mat == 3) ? s3 : s4;
#pragma unroll
    for (int i = 0; i < 4; ++i){
        int idx = i * 256 + tid;          // 1024 float4 groups: 64 c x 16 g
        int cc = idx >> 4, g = idx & 15;
        float4 v = *(const float4*)(s + (size_t)(c0 + cc) * 64 + g * 4);
        T[cc][g * 4 + 0] = v.x; T[cc][g * 4 + 1] = v.y;
        T[cc][g * 4 + 2] = v.z; T[cc][g * 4 + 3] = v.w;
    }
    __syncthreads();
    size_t base = ((size_t)mat * 32 + (c0 >> 6)) * 4096;
#pragma unroll
    for (int i = 0; i < 4; ++i){
        int idx = i * 256 + tid;          // 1024 ushort4: 64 h x 16 groups(of 4 kk)
        int h = idx >> 4, g = idx & 15;
        ushort4 u;
        u.x = f2us(T[g * 4 + 0][h]); u.y = f2us(T[g * 4 + 1][h]);
        u.z = f2us(T[g * 4 + 2][h]); u.w = f2us(T[g * 4 + 3][h]);
        *(ushort4*)(Wblk + base + (size_t)h * 64 + g * 4) = u;
    }
}

// ---------------- lx = hs[:, -1] ----------------
__global__ void k_lx(const float* __restrict__ hs, float* __restrict__ o){
    int i = blockIdx.x * 256 + threadIdx.x;
    if (i < TB * TC){
        int b = i >> 11, c = i & (TC - 1);
        o[i] = hs[((size_t)(b * TT + TT - 1)) * TC + c];
    }
}

// ---------------- gemm1 MFMA v4: round-10 structure, K split 16 ways for occupancy ----------------
// A (xxx) staged into wave-local LDS rows (same-wave DS FIFO => no barriers);
// B-frags loaded directly from L2-resident w1T[160][2048] in MFMA layout.
// grid (128 Mtiles, 16 Kchunks of 128), 256 thr, 4 steps/block
__global__ __launch_bounds__(256) void k_gemm1_mfma(
    const float* __restrict__ hs, const float* __restrict__ shift,
    const float* __restrict__ maax, const unsigned short* __restrict__ w1T,
    float* __restrict__ Gpart)
{
    __shared__ unsigned short As[64 * 40];    // [m][k] pad 40 (5 KB)
    int tid = threadIdx.x;
    int wv = tid >> 6, ln = tid & 63;
    int lm = ln & 15, lq = ln >> 4;
    int n0 = blockIdx.x * 64;
    int c0 = blockIdx.y * 128;
    f32x4 zero = {0.f, 0.f, 0.f, 0.f};
    f32x4 acc[10];
#pragma unroll
    for (int i = 0; i < 10; ++i) acc[i] = zero;

    // staging geometry (fixed per thread)
    int m = tid >> 2, kg = (tid & 3) * 8;
    int n = n0 + m; int t = n & (TT - 1); int b = n >> 12;
    const float* hp_base = hs + (size_t)n * TC + kg;
    const float* pp_base = (t == 0) ? (shift + (size_t)b * TC + kg) : (hp_base - TC);

    for (int step = 0; step < 4; ++step){
        int kk0 = c0 + step * 32;
        {   // A staging: xxx on the fly (wave-local rows)
            const float* hp = hp_base + kk0;
            const float* pp = pp_base + kk0;
            float4 h0 = *(const float4*)hp,      h1 = *(const float4*)(hp + 4);
            float4 p0 = *(const float4*)pp,      p1 = *(const float4*)(pp + 4);
            float4 m0 = *(const float4*)(maax + kk0 + kg), m1 = *(const float4*)(maax + kk0 + kg + 4);
            ushort4 ua, ub;
            ua.x = f2us(h0.x + (p0.x - h0.x) * m0.x);
            ua.y = f2us(h0.y + (p0.y - h0.y) * m0.y);
            ua.z = f2us(h0.z + (p0.z - h0.z) * m0.z);
            ua.w = f2us(h0.w + (p0.w - h0.w) * m0.w);
            ub.x = f2us(h1.x + (p1.x - h1.x) * m1.x);
            ub.y = f2us(h1.y + (p1.y - h1.y) * m1.y);
            ub.z = f2us(h1.z + (p1.z - h1.z) * m1.z);
            ub.w = f2us(h1.w + (p1.w - h1.w) * m1.w);
            *(ushort4*)(As + m * 40 + kg) = ua;
            *(ushort4*)(As + m * 40 + kg + 4) = ub;
        }
        // same-wave ds_write -> ds_read: FIFO ordered, no barrier
        bf16x8 af = *(const bf16x8*)(As + (wv * 16 + lm) * 40 + lq * 8);
        const unsigned short* bp = w1T + kk0 + lq * 8;
#pragma unroll
        for (int nt = 0; nt < 10; ++nt){
            bf16x8 bf_ = *(const bf16x8*)(bp + (size_t)(nt * 16 + lm) * TC);
            acc[nt] = __builtin_amdgcn_mfma_f32_16x16x32_bf16(af, bf_, acc[nt], 0, 0, 0);
        }
    }
    float* gp = Gpart + (size_t)blockIdx.y * TM * 160;
#pragma unroll
    for (int nt = 0; nt < 10; ++nt)
#pragma unroll
        for (int i = 0; i < 4; ++i){
            int nn = n0 + wv * 16 + lq * 4 + i;
            gp[(size_t)nn * 160 + nt * 16 + lm] = acc[nt][i];
        }
}

// ---------------- G1b = bf16(tanh(sum Gpart)) over 16 K-slices ----------------
__global__ void k_g1tanhb(const float* __restrict__ Gpart, unsigned short* __restrict__ G1b){
    int i = blockIdx.x * 256 + threadIdx.x;   // 327680 float4
    if (i < 327680){
        float4 s = {0.f, 0.f, 0.f, 0.f};
        for (int kc = 0; kc < 16; ++kc){
            float4 g = *(const float4*)(Gpart + (size_t)kc * TM * 160 + (size_t)i * 4);
            s.x += g.x; s.y += g.y; s.z += g.z; s.w += g.w;
        }
        ushort4 o;
        o.x = f2us(tanhf(s.x)); o.y = f2us(tanhf(s.y));
        o.z = f2us(tanhf(s.z)); o.w = f2us(tanhf(s.w));
        *(ushort4*)(G1b + (size_t)i * 4) = o;
    }
}

// ---------------- mix MFMA v2: direct-global fragments, Xt-only LDS ----------------
// grid (128 M, 32 N), 256 thr
__global__ __launch_bounds__(256) void k_mix_mfma(
    const float* __restrict__ hs, const float* __restrict__ shift,
    const unsigned short* __restrict__ G1b, const unsigned short* __restrict__ w2T,
    const float* __restrict__ maaw, const float* __restrict__ maak,
    const float* __restrict__ maav, const float* __restrict__ maar,
    const float* __restrict__ maag,
    unsigned short* __restrict__ X5)
{
    __shared__ unsigned short Xt[64 * 76];      // stride 76 shorts: conflict-free epilogue
    int tid = threadIdx.x;
    int wv = tid >> 6, ln = tid & 63;
    int lm = ln & 15, lq = ln >> 4;
    int n0 = blockIdx.x * 64, c0 = blockIdx.y * 64;

    float hv[4][4], dv[4][4];
#pragma unroll
    for (int nt = 0; nt < 4; ++nt){
        int c = c0 + nt * 16 + lm;
#pragma unroll
        for (int i = 0; i < 4; ++i){
            int n = n0 + wv * 16 + lq * 4 + i;
            float h = hs[(size_t)n * TC + c];
            float p = ((n & (TT - 1)) == 0) ? shift[(size_t)(n >> 12) * TC + c]
                                            : hs[(size_t)(n - 1) * TC + c];
            hv[nt][i] = h; dv[nt][i] = p - h;
        }
    }
    bf16x8 af[5];
    {
        const unsigned short* gp = G1b + (size_t)(n0 + wv * 16 + lm) * 160 + lq * 8;
#pragma unroll
        for (int f = 0; f < 5; ++f) af[f] = *(const bf16x8*)(gp + f * 32);
    }
    f32x4 zero = {0.f, 0.f, 0.f, 0.f};
    const float* mas[5] = {maaw, maak, maav, maar, maag};
    int rr = tid >> 3, gg = tid & 7;
#pragma unroll
    for (int f = 0; f < 5; ++f){
        const unsigned short* wp = w2T + ((size_t)f * TC + c0) * 32 + lq * 8;
        f32x4 am[4];
#pragma unroll
        for (int nt = 0; nt < 4; ++nt){
            bf16x8 bm = *(const bf16x8*)(wp + (size_t)(nt * 16 + lm) * 32);
            am[nt] = __builtin_amdgcn_mfma_f32_16x16x32_bf16(af[f], bm, zero, 0, 0, 0);
        }
#pragma unroll
        for (int nt = 0; nt < 4; ++nt){
            float ma = mas[f][c0 + nt * 16 + lm];
#pragma unroll
            for (int i = 0; i < 4; ++i)
                Xt[(wv * 16 + lq * 4 + i) * 76 + nt * 16 + lm] =
                    f2us(hv[nt][i] + dv[nt][i] * (ma + am[nt][i]));
        }
        __syncthreads();
        unsigned short* plane = X5 + (size_t)f * TM * TC;
#pragma unroll
        for (int p = 0; p < 2; ++p){
            int r = p * 32 + rr;
            uint4 v = *(const uint4*)(Xt + r * 76 + gg * 8);
            *(uint4*)(plane + (size_t)(n0 + r) * TC + c0 + gg * 8) = v;
        }
        __syncthreads();
    }
}

// ---------------- proj MFMA v5: m97-style double-buffered LDS staging ----------------
// grid (128 Mtiles of 64 rows, 5 mats), 256 thr, BK=64, 32 K-steps.
__global__ __launch_bounds__(256) void k_proj_mfma(
    const unsigned short* __restrict__ X5, const unsigned short* __restrict__ Wblk,
    float* __restrict__ rbuf, float* __restrict__ kbuf, float* __restrict__ vbuf,
    float* __restrict__ gpre, float* __restrict__ dpre)
{
    __shared__ unsigned short As[2][64 * 72];   // 18.4 KB
    __shared__ unsigned short Bs[2][64 * 72];   // 18.4 KB
    int tid = threadIdx.x;
    int wv = tid >> 6, ln = tid & 63;
    int lm = ln & 15, lq = ln >> 4;
    int n0 = blockIdx.x * 64;
    int mat = blockIdx.y;
    int pI = (mat == 0) ? 3 : (mat == 1) ? 1 : (mat == 2) ? 2 : (mat == 3) ? 4 : 0;
    const unsigned short* A = X5 + (size_t)pI * TM * TC;
    const unsigned short* Bm = Wblk + (size_t)mat * 32 * 4096;
    float* Out = (mat == 0) ? rbuf : (mat == 1) ? kbuf : (mat == 2) ? vbuf : (mat == 3) ? gpre : dpre;

    int r0 = tid >> 3, g0 = tid & 7;
    int r1 = (tid + 256) >> 3, g1 = tid & 7;
    int lofs = r0 * 72 + g0 * 8;
    int lofs1 = r1 * 72 + g1 * 8;

    f32x4 zero = {0.f, 0.f, 0.f, 0.f};
    f32x4 acc[4];
#pragma unroll
    for (int i = 0; i < 4; ++i) acc[i] = zero;

    {
        uint4 a0 = *(const uint4*)(A + (size_t)(n0 + r0) * TC + g0 * 8);
        uint4 a1 = *(const uint4*)(A + (size_t)(n0 + r1) * TC + g1 * 8);
        uint4 b0 = *(const uint4*)(Bm + (size_t)tid * 8);
        uint4 b1 = *(const uint4*)(Bm + (size_t)(tid + 256) * 8);
        *(uint4*)(&As[0][lofs]) = a0; *(uint4*)(&As[0][lofs1]) = a1;
        *(uint4*)(&Bs[0][lofs]) = b0; *(uint4*)(&Bs[0][lofs1]) = b1;
    }
    __syncthreads();

    for (int s = 0; s < 32; ++s){
        int cur = s & 1, nxt = cur ^ 1;
        uint4 a0, a1, b0, b1;
        if (s < 31){
            int kk0 = (s + 1) * 64;
            a0 = *(const uint4*)(A + (size_t)(n0 + r0) * TC + kk0 + g0 * 8);
            a1 = *(const uint4*)(A + (size_t)(n0 + r1) * TC + kk0 + g1 * 8);
            b0 = *(const uint4*)(Bm + (size_t)(s + 1) * 4096 + (size_t)tid * 8);
            b1 = *(const uint4*)(Bm + (size_t)(s + 1) * 4096 + (size_t)(tid + 256) * 8);
        }
#pragma unroll
        for (int ks = 0; ks < 2; ++ks){
            bf16x8 af = *(const bf16x8*)(&As[cur][(wv * 16 + lm) * 72 + ks * 32 + lq * 8]);
#pragma unroll
            for (int nt = 0; nt < 4; ++nt){
                bf16x8 bw = *(const bf16x8*)(&Bs[cur][(nt * 16 + lm) * 72 + ks * 32 + lq * 8]);
                acc[nt] = __builtin_amdgcn_mfma_f32_16x16x32_bf16(af, bw, acc[nt], 0, 0, 0);
            }
        }
        if (s < 31){
            *(uint4*)(&As[nxt][lofs]) = a0; *(uint4*)(&As[nxt][lofs1]) = a1;
            *(uint4*)(&Bs[nxt][lofs]) = b0; *(uint4*)(&Bs[nxt][lofs1]) = b1;
        }
        __syncthreads();
    }
#pragma unroll
    for (int nt = 0; nt < 4; ++nt)
#pragma unroll
        for (int i = 0; i < 4; ++i){
            int n = n0 + wv * 16 + lq * 4 + i;
            Out[(size_t)n * THD + nt * 16 + lm] = acc[nt][i];
        }
}

// ---------------- logw = -exp(time_decay + tanh(dpre) @ dw2) ----------------
__global__ __launch_bounds__(256) void k_wdecay(
    const float* __restrict__ dpre, const float* __restrict__ dw2,
    const float* __restrict__ tdec, float* __restrict__ logwb)
{
    __shared__ float W2s[64][65];
    __shared__ float Ths[16][65];
    int tid = threadIdx.x;
    int n0 = blockIdx.x * 16;
    for (int i = 0; i < 16; ++i){
        int flat = i * 256 + tid;
        W2s[flat >> 6][flat & 63] = dw2[flat];
    }
    for (int i = 0; i < 4; ++i){
        int flat = i * 256 + tid;
        int tt = flat >> 6, j = flat & 63;
        Ths[tt][j] = tanhf(dpre[(size_t)(n0 + tt) * THD + j]);
    }
    __syncthreads();
    int hh = tid & 63, tg = tid >> 6;
    float td = tdec[hh];
#pragma unroll
    for (int ii = 0; ii < 4; ++ii){
        int tt = tg * 4 + ii;
        float a = 0.f;
#pragma unroll 8
        for (int j = 0; j < 64; ++j) a += Ths[tt][j] * W2s[j][hh];
        logwb[(size_t)(n0 + tt) * THD + hh] = -expf(td + a);
    }
}

// ---------------- scan pass A ----------------
__global__ __launch_bounds__(256) void k_scanA(
    const float* __restrict__ kbuf, const float* __restrict__ vbuf,
    const float* __restrict__ logwb,
    float* __restrict__ chI, float* __restrict__ chP)
{
    __shared__ float kl[32][65], vl[32][65], ewl[32][65];
    int tid = threadIdx.x;
    int b = blockIdx.x >> 6, ch = blockIdx.x & 63;
    int w = tid >> 6, v = tid & 63, kb = w * 16;
    float s[16];
#pragma unroll
    for (int i = 0; i < 16; ++i) s[i] = 0.f;
    float p = 1.f;
    for (int ph = 0; ph < 2; ++ph){
        int t0 = b * TT + ch * 64 + ph * 32;
        for (int i = 0; i < 8; ++i){
            int flat = i * 256 + tid;
            int tt = flat >> 6, j = flat & 63;
            size_t g = (size_t)(t0 + tt) * THD + j;
            kl[tt][j] = kbuf[g];
            vl[tt][j] = vbuf[g];
            ewl[tt][j] = expf(logwb[g]);
        }
        __syncthreads();
        if (tid < 64){
#pragma unroll 8
            for (int t = 0; t < 32; ++t) p *= ewl[t][tid];
        }
        for (int t = 0; t < 32; ++t){
            float vv = vl[t][v];
#pragma unroll
            for (int i = 0; i < 16; ++i){
                float e = ewl[t][kb + i], kk = kl[t][kb + i];
                s[i] = s[i] * e + kk * vv;
            }
        }
        __syncthreads();
    }
    size_t base = ((size_t)(b * TNCH + ch)) * THD * THD;
#pragma unroll
    for (int i = 0; i < 16; ++i) chI[base + (size_t)(kb + i) * THD + v] = s[i];
    if (tid < 64) chP[(size_t)(b * TNCH + ch) * THD + tid] = p;
}

// ---------------- scan pass B (32 blocks: b x 4-krow groups, 1 elem/thread) ----------------
__global__ __launch_bounds__(256) void k_scanB(
    const float* __restrict__ chI, const float* __restrict__ chP,
    const float* __restrict__ wkv0,
    float* __restrict__ chS0, float* __restrict__ sfin)
{
    int tid = threadIdx.x;
    int blk = blockIdx.x;                       // 0..31
    int b = blk >> 4;
    int kr = (blk & 15) * 4 + (tid >> 6);       // k-row
    int v = tid & 63;
    float s = wkv0[(size_t)b * THD * THD + (size_t)kr * THD + v];
    for (int ch = 0; ch < TNCH; ++ch){
        size_t base = (size_t)(b * TNCH + ch);
        float P = chP[base * THD + kr];
        float I = chI[base * THD * THD + (size_t)kr * THD + v];
        chS0[base * THD * THD + (size_t)kr * THD + v] = s;
        s = s * P + I;
    }
    sfin[(size_t)b * THD * THD + (size_t)kr * THD + v] = s;
}

// ---------------- scan pass C ----------------
__global__ __launch_bounds__(256) void k_scanC(
    const float* __restrict__ rbuf, const float* __restrict__ kbuf,
    const float* __restrict__ vbuf, const float* __restrict__ logwb,
    const float* __restrict__ chS0, const float* __restrict__ faaaa,
    float* __restrict__ obuf)
{
    __shared__ float rl[32][65], kl[32][65], vl[32][65], ewl[32][65];
    __shared__ float part[4][64];
    __shared__ float ruk[32];
    __shared__ float ul[64];
    int tid = threadIdx.x;
    int b = blockIdx.x >> 6, ch = blockIdx.x & 63;
    int w = tid >> 6, v = tid & 63, kb = w * 16;
    if (tid < 64) ul[tid] = faaaa[tid];
    float s[16];
    {
        size_t base = ((size_t)(b * TNCH + ch)) * THD * THD;
#pragma unroll
        for (int i = 0; i < 16; ++i) s[i] = chS0[base + (size_t)(kb + i) * THD + v];
    }
    for (int ph = 0; ph < 2; ++ph){
        int t0 = b * TT + ch * 64 + ph * 32;
        for (int i = 0; i < 8; ++i){
            int flat = i * 256 + tid;
            int tt = flat >> 6, j = flat & 63;
            size_t g = (size_t)(t0 + tt) * THD + j;
            rl[tt][j] = rbuf[g];
            kl[tt][j] = kbuf[g];
            vl[tt][j] = vbuf[g];
            ewl[tt][j] = expf(logwb[g]);
        }
        __syncthreads();
        if (tid < 32){
            float a = 0.f;
#pragma unroll 8
            for (int k = 0; k < 64; ++k) a += rl[tid][k] * ul[k] * kl[tid][k];
            ruk[tid] = a;
        }
        __syncthreads();
        for (int t = 0; t < 32; ++t){
            float vv = vl[t][v];
            float pp = 0.f;
#pragma unroll
            for (int i = 0; i < 16; ++i) pp += rl[t][kb + i] * s[i];
            part[w][v] = pp;
            __syncthreads();
            if (w == 0){
                float o = part[0][v] + part[1][v] + part[2][v] + part[3][v] + ruk[t] * vv;
                obuf[(size_t)(t0 + t) * THD + v] = o;
            }
#pragma unroll
            for (int i = 0; i < 16; ++i){
                float e = ewl[t][kb + i], kk = kl[t][kb + i];
                s[i] = s[i] * e + kk * vv;
            }
            __syncthreads();
        }
    }
}

// ---------------- out MFMA: out = (o*silu(g)) @ Wo ----------------
// grid (128 M, 16 N-tiles of 128), 256 thr
__global__ __launch_bounds__(256) void k_out_mfma(
    const float* __restrict__ obuf, const float* __restrict__ gpre,
    const unsigned short* __restrict__ Wob, float* __restrict__ outp)
{
    __shared__ unsigned short As[64 * 72];    // [m][k=64] pad 72
    __shared__ unsigned short Bs[128 * 72];   // [n][k=64] pad 72
    int tid = threadIdx.x;
    int wv = tid >> 6, ln = tid & 63;
    int lm = ln & 15, lq = ln >> 4;
    int n0 = blockIdx.x * 64, c0 = blockIdx.y * 128;

    for (int i = tid; i < 1024; i += 256){   // 64 rows x 16 f4-groups
        int r = i >> 4, g = i & 15;
        size_t base = (size_t)(n0 + r) * THD + g * 4;
        float4 ov = *(const float4*)(obuf + base);
        float4 gv = *(const float4*)(gpre + base);
        ushort4 u;
        u.x = f2us(ov.x * (gv.x / (1.f + expf(-gv.x))));
        u.y = f2us(ov.y * (gv.y / (1.f + expf(-gv.y))));
        u.z = f2us(ov.z * (gv.z / (1.f + expf(-gv.z))));
        u.w = f2us(ov.w * (gv.w / (1.f + expf(-gv.w))));
        *(ushort4*)(As + r * 72 + g * 4) = u;
    }
    for (int i = tid; i < 1024; i += 256){   // 64 k x 16 groups(of 8 n)
        int k = i >> 4, ng = i & 15;
        uint4 w4 = *(const uint4*)(Wob + (size_t)k * TC + c0 + ng * 8);
        const unsigned short* ww = (const unsigned short*)&w4;
#pragma unroll
        for (int j = 0; j < 8; ++j) Bs[(ng * 8 + j) * 72 + k] = ww[j];
    }
    __syncthreads();

    f32x4 zero = {0.f, 0.f, 0.f, 0.f};
    f32x4 acc[8];
#pragma unroll
    for (int i = 0; i < 8; ++i) acc[i] = zero;
#pragma unroll
    for (int ks = 0; ks < 2; ++ks){
        bf16x8 af = *(const bf16x8*)(As + (wv * 16 + lm) * 72 + ks * 32 + lq * 8);
#pragma unroll
        for (int nt = 0; nt < 8; ++nt){
            bf16x8 bf_ = *(const bf16x8*)(Bs + (nt * 16 + lm) * 72 + ks * 32 + lq * 8);
            acc[nt] = __builtin_amdgcn_mfma_f32_16x16x32_bf16(af, bf_, acc[nt], 0, 0, 0);
        }
    }
#pragma unroll
    for (int nt = 0; nt < 8; ++nt)
#pragma unroll
        for (int i = 0; i < 4; ++i){
            int n = n0 + wv * 16 + lq * 4 + i;
            outp[(size_t)n * TC + c0 + nt * 16 + lm] = acc[nt][i];
        }
}

extern "C" void kernel_launch(void* const* d_in, const int* in_sizes, int n_in,
                              void* d_out, int out_size, void* d_ws, size_t ws_size,
                              hipStream_t stream)
{
    const float* hs    = (const float*)d_in[0];
    const float* shift = (const float*)d_in[1];
    const float* wkv0  = (const float*)d_in[2];
    const float* maax  = (const float*)d_in[3];
    const float* maaw  = (const float*)d_in[4];
    const float* maak  = (const float*)d_in[5];
    const float* maav  = (const float*)d_in[6];
    const float* maar  = (const float*)d_in[7];
    const float* maag  = (const float*)d_in[8];
    const float* w1    = (const float*)d_in[9];
    const float* w2    = (const float*)d_in[10];
    const float* tdec  = (const float*)d_in[11];
    const float* dw1   = (const float*)d_in[12];
    const float* dw2   = (const float*)d_in[13];
    const float* faaaa = (const float*)d_in[14];
    const float* Wr    = (const float*)d_in[15];
    const float* Wk    = (const float*)d_in[16];
    const float* Wv    = (const float*)d_in[17];
    const float* Wg    = (const float*)d_in[18];
    const float* Wo    = (const float*)d_in[19];

    if (ws_size < 186384384ULL) return;

    char* ws = (char*)d_ws;
    unsigned short* w1T  = (unsigned short*)(ws + 0);             // 160x2048 bf16 (transposed)
    unsigned short* w2T  = (unsigned short*)(ws + 655360);        // 5x2048x32 bf16 (transposed)
    unsigned short* Wblk = (unsigned short*)(ws + 1310720);       // 5x32x64x64 bf16 (K-blocked)
    unsigned short* Wob  = (unsigned short*)(ws + 2621440);       // 64x2048 bf16
    unsigned short* G1b  = (unsigned short*)(ws + 2883584);       // 8192x160 bf16
    char*           x5r  = ws + 8126464;                          // 168 MB region
    unsigned short* X5   = (unsigned short*)x5r;                  // 5 planes bf16
    float*          Gpart= (float*)x5r;                           // alias (pre-mix lifetime, 16 slices = 84 MB)
    float*          logwb= (float*)(x5r + 0);                     // alias (post-proj lifetime)
    float*          obuf = (float*)(x5r + 2097152);
    float*          chI  = (float*)(x5r + 4194304);
    float*          chS0 = (float*)(x5r + 6291456);
    float*          chP  = (float*)(x5r + 8388608);
    float*          rbuf = (float*)(ws + 175898624);
    float*          kbuf = (float*)(ws + 177995776);
    float*          vbuf = (float*)(ws + 180092928);
    float*          gpre = (float*)(ws + 182190080);
    float*          dpre = (float*)(ws + 184287232);

    float* outp = (float*)d_out;
    float* lxp  = outp + (size_t)TM * TC;
    float* sfin = lxp + (size_t)TB * TC;

    k_w1t   <<<32, 256, 0, stream>>>(w1, w1T);
    k_cvt   <<<128, 256, 0, stream>>>(Wo, Wob, 32768);
    k_w2t   <<<dim3(32, 5), 256, 0, stream>>>(w2, w2T);
    k_cvt5t <<<dim3(32, 5), 256, 0, stream>>>(Wr, Wk, Wv, Wg, dw1, Wblk);
    k_lx    <<<16, 256, 0, stream>>>(hs, lxp);

    k_gemm1_mfma <<<dim3(128, 16), 256, 0, stream>>>(hs, shift, maax, w1T, Gpart);
    k_g1tanhb    <<<1280, 256, 0, stream>>>(Gpart, G1b);
    k_mix_mfma   <<<dim3(128, 32), 256, 0, stream>>>(hs, shift, G1b, w2T,
                                                     maaw, maak, maav, maar, maag, X5);
    k_proj_mfma  <<<dim3(128, 5), 256, 0, stream>>>(X5, Wblk, rbuf, kbuf, vbuf, gpre, dpre);
    k_wdecay     <<<512, 256, 0, stream>>>(dpre, dw2, tdec, logwb);
    k_scanA      <<<128, 256, 0, stream>>>(kbuf, vbuf, logwb, chI, chP);
    k_scanB      <<<32, 256, 0, stream>>>(chI, chP, wkv0, chS0, sfin);
    k_scanC      <<<128, 256, 0, stream>>>(rbuf, kbuf, vbuf, logwb, chS0, faaaa, obuf);
    k_out_mfma   <<<dim3(128, 16), 256, 0, stream>>>(obuf, gpre, Wob, outp);
}

// Round 13
// 359.151 us; speedup vs baseline: 1.0978x; 1.0978x over previous
//
#include <hip/hip_runtime.h>

#define TB 2
#define TT 4096
#define TC 2048
#define TM 8192          // B*T
#define THD 64
#define TNCH 128         // chunks per batch (32 steps each)

typedef __attribute__((ext_vector_type(8))) short bf16x8;
typedef __attribute__((ext_vector_type(4))) float f32x4;

__device__ __forceinline__ float us2f(unsigned short u){
    union { unsigned int u; float f; } x; x.u = ((unsigned int)u) << 16; return x.f;
}
__device__ __forceinline__ unsigned short f2us(float f){
    unsigned int u = __float_as_uint(f);
    unsigned int r = (u + 0x7fffu + ((u >> 16) & 1u)) >> 16;   // RNE bf16
    return (unsigned short)r;
}

// ---------------- generic fp32 -> bf16 convert ----------------
__global__ void k_cvt(const float* __restrict__ src, unsigned short* __restrict__ dst, int n4){
    int i = blockIdx.x * 256 + threadIdx.x;
    if (i < n4){
        float4 v = *(const float4*)(src + (size_t)i * 4);
        ushort4 u; u.x = f2us(v.x); u.y = f2us(v.y); u.z = f2us(v.z); u.w = f2us(v.w);
        *(ushort4*)(dst + (size_t)i * 4) = u;
    }
}

// ---------------- w1 [2048][160] f32 -> w1T [160][2048] bf16 ----------------
// grid 32 (ktiles of 64), 256 thr
__global__ void k_w1t(const float* __restrict__ w1, unsigned short* __restrict__ w1T){
    __shared__ float T[64][164];
    int tid = threadIdx.x;
    int k0 = blockIdx.x * 64;
    for (int i = tid; i < 2560; i += 256){   // 64 k x 40 float4-groups
        int kk = i / 40, g = i % 40;
        float4 v = *(const float4*)(w1 + (size_t)(k0 + kk) * 160 + g * 4);
        T[kk][g * 4 + 0] = v.x; T[kk][g * 4 + 1] = v.y;
        T[kk][g * 4 + 2] = v.z; T[kk][g * 4 + 3] = v.w;
    }
    __syncthreads();
    for (int i = tid; i < 2560; i += 256){   // 160 n x 16 groups (4 k each)
        int n = i >> 4, g = i & 15;
        ushort4 u;
        u.x = f2us(T[g * 4 + 0][n]); u.y = f2us(T[g * 4 + 1][n]);
        u.z = f2us(T[g * 4 + 2][n]); u.w = f2us(T[g * 4 + 3][n]);
        *(ushort4*)(w1T + (size_t)n * TC + k0 + g * 4) = u;
    }
}

// ---------------- w2 [5][32][2048] f32 -> w2T [5][2048][32] bf16 ----------------
// grid (32 ctiles, 5 f), 256 thr
__global__ void k_w2t(const float* __restrict__ w2, unsigned short* __restrict__ w2T){
    __shared__ float T[32][65];
    int tid = threadIdx.x;
    int f = blockIdx.y, c0 = blockIdx.x * 64;
#pragma unroll
    for (int i = 0; i < 2; ++i){
        int idx = i * 256 + tid;          // 512 float4 groups: 32 d x 16 g
        int d = idx >> 4, g = idx & 15;
        float4 v = *(const float4*)(w2 + ((size_t)f * 32 + d) * TC + c0 + g * 4);
        T[d][g * 4 + 0] = v.x; T[d][g * 4 + 1] = v.y;
        T[d][g * 4 + 2] = v.z; T[d][g * 4 + 3] = v.w;
    }
    __syncthreads();
    int cc = tid >> 2, g = tid & 3;       // 64 c x 4 groups(of 8 d)
    unsigned short* dst = w2T + ((size_t)f * TC + c0 + cc) * 32 + g * 8;
    ushort4 u0, u1;
    u0.x = f2us(T[g * 8 + 0][cc]); u0.y = f2us(T[g * 8 + 1][cc]);
    u0.z = f2us(T[g * 8 + 2][cc]); u0.w = f2us(T[g * 8 + 3][cc]);
    u1.x = f2us(T[g * 8 + 4][cc]); u1.y = f2us(T[g * 8 + 5][cc]);
    u1.z = f2us(T[g * 8 + 6][cc]); u1.w = f2us(T[g * 8 + 7][cc]);
    *(ushort4*)dst = u0; *(ushort4*)(dst + 4) = u1;
}

// ---------------- {Wr,Wk,Wv,Wg,dw1}[2048][64] f32 -> Wblk[mat][32 kb][64 h][64 kk] bf16 ----------------
// grid (32 ctiles, 5 mats), 256 thr
__global__ void k_cvt5t(const float* __restrict__ s0, const float* __restrict__ s1,
                        const float* __restrict__ s2, const float* __restrict__ s3,
                        const float* __restrict__ s4, unsigned short* __restrict__ Wblk){
    __shared__ float T[64][65];
    int tid = threadIdx.x;
    int mat = blockIdx.y, c0 = blockIdx.x * 64;    // c0 = kb*64
    const float* s = (mat == 0) ? s0 : (mat == 1) ? s1 : (mat == 2) ? s2 : (mat == 3) ? s3 : s4;
#pragma unroll
    for (int i = 0; i < 4; ++i){
        int idx = i * 256 + tid;          // 1024 float4 groups: 64 c x 16 g
        int cc = idx >> 4, g = idx & 15;
        float4 v = *(const float4*)(s + (size_t)(c0 + cc) * 64 + g * 4);
        T[cc][g * 4 + 0] = v.x; T[cc][g * 4 + 1] = v.y;
        T[cc][g * 4 + 2] = v.z; T[cc][g * 4 + 3] = v.w;
    }
    __syncthreads();
    size_t base = ((size_t)mat * 32 + (c0 >> 6)) * 4096;
#pragma unroll
    for (int i = 0; i < 4; ++i){
        int idx = i * 256 + tid;          // 1024 ushort4: 64 h x 16 groups(of 4 kk)
        int h = idx >> 4, g = idx & 15;
        ushort4 u;
        u.x = f2us(T[g * 4 + 0][h]); u.y = f2us(T[g * 4 + 1][h]);
        u.z = f2us(T[g * 4 + 2][h]); u.w = f2us(T[g * 4 + 3][h]);
        *(ushort4*)(Wblk + base + (size_t)h * 64 + g * 4) = u;
    }
}

// ---------------- lx = hs[:, -1] ----------------
__global__ void k_lx(const float* __restrict__ hs, float* __restrict__ o){
    int i = blockIdx.x * 256 + threadIdx.x;
    if (i < TB * TC){
        int b = i >> 11, c = i & (TC - 1);
        o[i] = hs[((size_t)(b * TT + TT - 1)) * TC + c];
    }
}

// ---------------- gemm1 MFMA (round-10 proven): barrier-free, B direct from w1T ----------------
// grid (128 Mtiles, 8 Kchunks of 256), 256 thr, 8 steps/block
__global__ __launch_bounds__(256) void k_gemm1_mfma(
    const float* __restrict__ hs, const float* __restrict__ shift,
    const float* __restrict__ maax, const unsigned short* __restrict__ w1T,
    float* __restrict__ Gpart)
{
    __shared__ unsigned short As[64 * 40];    // [m][k] pad 40 (5 KB)
    int tid = threadIdx.x;
    int wv = tid >> 6, ln = tid & 63;
    int lm = ln & 15, lq = ln >> 4;
    int n0 = blockIdx.x * 64;
    int c0 = blockIdx.y * 256;
    f32x4 zero = {0.f, 0.f, 0.f, 0.f};
    f32x4 acc[10];
#pragma unroll
    for (int i = 0; i < 10; ++i) acc[i] = zero;

    // staging geometry (fixed per thread)
    int m = tid >> 2, kg = (tid & 3) * 8;
    int n = n0 + m; int t = n & (TT - 1); int b = n >> 12;
    const float* hp_base = hs + (size_t)n * TC + kg;
    const float* pp_base = (t == 0) ? (shift + (size_t)b * TC + kg) : (hp_base - TC);

    for (int step = 0; step < 8; ++step){
        int kk0 = c0 + step * 32;
        {   // A staging: xxx on the fly (wave-local rows)
            const float* hp = hp_base + kk0;
            const float* pp = pp_base + kk0;
            float4 h0 = *(const float4*)hp,      h1 = *(const float4*)(hp + 4);
            float4 p0 = *(const float4*)pp,      p1 = *(const float4*)(pp + 4);
            float4 m0 = *(const float4*)(maax + kk0 + kg), m1 = *(const float4*)(maax + kk0 + kg + 4);
            ushort4 ua, ub;
            ua.x = f2us(h0.x + (p0.x - h0.x) * m0.x);
            ua.y = f2us(h0.y + (p0.y - h0.y) * m0.y);
            ua.z = f2us(h0.z + (p0.z - h0.z) * m0.z);
            ua.w = f2us(h0.w + (p0.w - h0.w) * m0.w);
            ub.x = f2us(h1.x + (p1.x - h1.x) * m1.x);
            ub.y = f2us(h1.y + (p1.y - h1.y) * m1.y);
            ub.z = f2us(h1.z + (p1.z - h1.z) * m1.z);
            ub.w = f2us(h1.w + (p1.w - h1.w) * m1.w);
            *(ushort4*)(As + m * 40 + kg) = ua;
            *(ushort4*)(As + m * 40 + kg + 4) = ub;
        }
        // same-wave ds_write -> ds_read: FIFO ordered, no barrier
        bf16x8 af = *(const bf16x8*)(As + (wv * 16 + lm) * 40 + lq * 8);
        const unsigned short* bp = w1T + kk0 + lq * 8;
#pragma unroll
        for (int nt = 0; nt < 10; ++nt){
            bf16x8 bf_ = *(const bf16x8*)(bp + (size_t)(nt * 16 + lm) * TC);
            acc[nt] = __builtin_amdgcn_mfma_f32_16x16x32_bf16(af, bf_, acc[nt], 0, 0, 0);
        }
    }
    float* gp = Gpart + (size_t)blockIdx.y * TM * 160;
#pragma unroll
    for (int nt = 0; nt < 10; ++nt)
#pragma unroll
        for (int i = 0; i < 4; ++i){
            int nn = n0 + wv * 16 + lq * 4 + i;
            gp[(size_t)nn * 160 + nt * 16 + lm] = acc[nt][i];
        }
}

// ---------------- G1b = bf16(tanh(sum Gpart)) over 8 K-slices ----------------
__global__ void k_g1tanhb(const float* __restrict__ Gpart, unsigned short* __restrict__ G1b){
    int i = blockIdx.x * 256 + threadIdx.x;   // 327680 float4
    if (i < 327680){
        float4 s = {0.f, 0.f, 0.f, 0.f};
        for (int kc = 0; kc < 8; ++kc){
            float4 g = *(const float4*)(Gpart + (size_t)kc * TM * 160 + (size_t)i * 4);
            s.x += g.x; s.y += g.y; s.z += g.z; s.w += g.w;
        }
        ushort4 o;
        o.x = f2us(tanhf(s.x)); o.y = f2us(tanhf(s.y));
        o.z = f2us(tanhf(s.z)); o.w = f2us(tanhf(s.w));
        *(ushort4*)(G1b + (size_t)i * 4) = o;
    }
}

// ---------------- mix MFMA v2: direct-global fragments, Xt-only LDS ----------------
// grid (128 M, 32 N), 256 thr
__global__ __launch_bounds__(256) void k_mix_mfma(
    const float* __restrict__ hs, const float* __restrict__ shift,
    const unsigned short* __restrict__ G1b, const unsigned short* __restrict__ w2T,
    const float* __restrict__ maaw, const float* __restrict__ maak,
    const float* __restrict__ maav, const float* __restrict__ maar,
    const float* __restrict__ maag,
    unsigned short* __restrict__ X5)
{
    __shared__ unsigned short Xt[64 * 76];      // stride 76 shorts: conflict-free epilogue
    int tid = threadIdx.x;
    int wv = tid >> 6, ln = tid & 63;
    int lm = ln & 15, lq = ln >> 4;
    int n0 = blockIdx.x * 64, c0 = blockIdx.y * 64;

    float hv[4][4], dv[4][4];
#pragma unroll
    for (int nt = 0; nt < 4; ++nt){
        int c = c0 + nt * 16 + lm;
#pragma unroll
        for (int i = 0; i < 4; ++i){
            int n = n0 + wv * 16 + lq * 4 + i;
            float h = hs[(size_t)n * TC + c];
            float p = ((n & (TT - 1)) == 0) ? shift[(size_t)(n >> 12) * TC + c]
                                            : hs[(size_t)(n - 1) * TC + c];
            hv[nt][i] = h; dv[nt][i] = p - h;
        }
    }
    bf16x8 af[5];
    {
        const unsigned short* gp = G1b + (size_t)(n0 + wv * 16 + lm) * 160 + lq * 8;
#pragma unroll
        for (int f = 0; f < 5; ++f) af[f] = *(const bf16x8*)(gp + f * 32);
    }
    f32x4 zero = {0.f, 0.f, 0.f, 0.f};
    const float* mas[5] = {maaw, maak, maav, maar, maag};
    int rr = tid >> 3, gg = tid & 7;
#pragma unroll
    for (int f = 0; f < 5; ++f){
        const unsigned short* wp = w2T + ((size_t)f * TC + c0) * 32 + lq * 8;
        f32x4 am[4];
#pragma unroll
        for (int nt = 0; nt < 4; ++nt){
            bf16x8 bm = *(const bf16x8*)(wp + (size_t)(nt * 16 + lm) * 32);
            am[nt] = __builtin_amdgcn_mfma_f32_16x16x32_bf16(af[f], bm, zero, 0, 0, 0);
        }
#pragma unroll
        for (int nt = 0; nt < 4; ++nt){
            float ma = mas[f][c0 + nt * 16 + lm];
#pragma unroll
            for (int i = 0; i < 4; ++i)
                Xt[(wv * 16 + lq * 4 + i) * 76 + nt * 16 + lm] =
                    f2us(hv[nt][i] + dv[nt][i] * (ma + am[nt][i]));
        }
        __syncthreads();
        unsigned short* plane = X5 + (size_t)f * TM * TC;
#pragma unroll
        for (int p = 0; p < 2; ++p){
            int r = p * 32 + rr;
            uint4 v = *(const uint4*)(Xt + r * 76 + gg * 8);
            *(uint4*)(plane + (size_t)(n0 + r) * TC + c0 + gg * 8) = v;
        }
        __syncthreads();
    }
}

// ---------------- proj MFMA v5: m97-style double-buffered LDS staging ----------------
// grid (128 Mtiles of 64 rows, 5 mats), 256 thr, BK=64, 32 K-steps.
__global__ __launch_bounds__(256) void k_proj_mfma(
    const unsigned short* __restrict__ X5, const unsigned short* __restrict__ Wblk,
    float* __restrict__ rbuf, float* __restrict__ kbuf, float* __restrict__ vbuf,
    float* __restrict__ gpre, float* __restrict__ dpre)
{
    __shared__ unsigned short As[2][64 * 72];   // 18.4 KB
    __shared__ unsigned short Bs[2][64 * 72];   // 18.4 KB
    int tid = threadIdx.x;
    int wv = tid >> 6, ln = tid & 63;
    int lm = ln & 15, lq = ln >> 4;
    int n0 = blockIdx.x * 64;
    int mat = blockIdx.y;
    int pI = (mat == 0) ? 3 : (mat == 1) ? 1 : (mat == 2) ? 2 : (mat == 3) ? 4 : 0;
    const unsigned short* A = X5 + (size_t)pI * TM * TC;
    const unsigned short* Bm = Wblk + (size_t)mat * 32 * 4096;
    float* Out = (mat == 0) ? rbuf : (mat == 1) ? kbuf : (mat == 2) ? vbuf : (mat == 3) ? gpre : dpre;

    int r0 = tid >> 3, g0 = tid & 7;
    int r1 = (tid + 256) >> 3, g1 = tid & 7;
    int lofs = r0 * 72 + g0 * 8;
    int lofs1 = r1 * 72 + g1 * 8;

    f32x4 zero = {0.f, 0.f, 0.f, 0.f};
    f32x4 acc[4];
#pragma unroll
    for (int i = 0; i < 4; ++i) acc[i] = zero;

    {
        uint4 a0 = *(const uint4*)(A + (size_t)(n0 + r0) * TC + g0 * 8);
        uint4 a1 = *(const uint4*)(A + (size_t)(n0 + r1) * TC + g1 * 8);
        uint4 b0 = *(const uint4*)(Bm + (size_t)tid * 8);
        uint4 b1 = *(const uint4*)(Bm + (size_t)(tid + 256) * 8);
        *(uint4*)(&As[0][lofs]) = a0; *(uint4*)(&As[0][lofs1]) = a1;
        *(uint4*)(&Bs[0][lofs]) = b0; *(uint4*)(&Bs[0][lofs1]) = b1;
    }
    __syncthreads();

    for (int s = 0; s < 32; ++s){
        int cur = s & 1, nxt = cur ^ 1;
        uint4 a0, a1, b0, b1;
        if (s < 31){
            int kk0 = (s + 1) * 64;
            a0 = *(const uint4*)(A + (size_t)(n0 + r0) * TC + kk0 + g0 * 8);
            a1 = *(const uint4*)(A + (size_t)(n0 + r1) * TC + kk0 + g1 * 8);
            b0 = *(const uint4*)(Bm + (size_t)(s + 1) * 4096 + (size_t)tid * 8);
            b1 = *(const uint4*)(Bm + (size_t)(s + 1) * 4096 + (size_t)(tid + 256) * 8);
        }
#pragma unroll
        for (int ks = 0; ks < 2; ++ks){
            bf16x8 af = *(const bf16x8*)(&As[cur][(wv * 16 + lm) * 72 + ks * 32 + lq * 8]);
#pragma unroll
            for (int nt = 0; nt < 4; ++nt){
                bf16x8 bw = *(const bf16x8*)(&Bs[cur][(nt * 16 + lm) * 72 + ks * 32 + lq * 8]);
                acc[nt] = __builtin_amdgcn_mfma_f32_16x16x32_bf16(af, bw, acc[nt], 0, 0, 0);
            }
        }
        if (s < 31){
            *(uint4*)(&As[nxt][lofs]) = a0; *(uint4*)(&As[nxt][lofs1]) = a1;
            *(uint4*)(&Bs[nxt][lofs]) = b0; *(uint4*)(&Bs[nxt][lofs1]) = b1;
        }
        __syncthreads();
    }
#pragma unroll
    for (int nt = 0; nt < 4; ++nt)
#pragma unroll
        for (int i = 0; i < 4; ++i){
            int n = n0 + wv * 16 + lq * 4 + i;
            Out[(size_t)n * THD + nt * 16 + lm] = acc[nt][i];
        }
}

// ---------------- logw = -exp(time_decay + tanh(dpre) @ dw2) ----------------
__global__ __launch_bounds__(256) void k_wdecay(
    const float* __restrict__ dpre, const float* __restrict__ dw2,
    const float* __restrict__ tdec, float* __restrict__ logwb)
{
    __shared__ float W2s[64][65];
    __shared__ float Ths[16][65];
    int tid = threadIdx.x;
    int n0 = blockIdx.x * 16;
    for (int i = 0; i < 16; ++i){
        int flat = i * 256 + tid;
        W2s[flat >> 6][flat & 63] = dw2[flat];
    }
    for (int i = 0; i < 4; ++i){
        int flat = i * 256 + tid;
        int tt = flat >> 6, j = flat & 63;
        Ths[tt][j] = tanhf(dpre[(size_t)(n0 + tt) * THD + j]);
    }
    __syncthreads();
    int hh = tid & 63, tg = tid >> 6;
    float td = tdec[hh];
#pragma unroll
    for (int ii = 0; ii < 4; ++ii){
        int tt = tg * 4 + ii;
        float a = 0.f;
#pragma unroll 8
        for (int j = 0; j < 64; ++j) a += Ths[tt][j] * W2s[j][hh];
        logwb[(size_t)(n0 + tt) * THD + hh] = -expf(td + a);
    }
}

// ---------------- scan pass A: 128 chunks of 32 steps ----------------
// grid 256 (= B * 128 chunks), 256 thr
__global__ __launch_bounds__(256) void k_scanA(
    const float* __restrict__ kbuf, const float* __restrict__ vbuf,
    const float* __restrict__ logwb,
    float* __restrict__ chI, float* __restrict__ chP)
{
    __shared__ float kl[32][65], vl[32][65], ewl[32][65];
    int tid = threadIdx.x;
    int b = blockIdx.x >> 7, ch = blockIdx.x & 127;
    int w = tid >> 6, v = tid & 63, kb = w * 16;
    float s[16];
#pragma unroll
    for (int i = 0; i < 16; ++i) s[i] = 0.f;
    float p = 1.f;
    int t0 = b * TT + ch * 32;
    for (int i = 0; i < 8; ++i){
        int flat = i * 256 + tid;
        int tt = flat >> 6, j = flat & 63;
        size_t g = (size_t)(t0 + tt) * THD + j;
        kl[tt][j] = kbuf[g];
        vl[tt][j] = vbuf[g];
        ewl[tt][j] = expf(logwb[g]);
    }
    __syncthreads();
    if (tid < 64){
#pragma unroll 8
        for (int t = 0; t < 32; ++t) p *= ewl[t][tid];
    }
    for (int t = 0; t < 32; ++t){
        float vv = vl[t][v];
#pragma unroll
        for (int i = 0; i < 16; ++i){
            float e = ewl[t][kb + i], kk = kl[t][kb + i];
            s[i] = s[i] * e + kk * vv;
        }
    }
    size_t base = ((size_t)(b * TNCH + ch)) * THD * THD;
#pragma unroll
    for (int i = 0; i < 16; ++i) chI[base + (size_t)(kb + i) * THD + v] = s[i];
    if (tid < 64) chP[(size_t)(b * TNCH + ch) * THD + tid] = p;
}

// ---------------- scan pass B (32 blocks: b x 4-krow groups, 1 elem/thread) ----------------
__global__ __launch_bounds__(256) void k_scanB(
    const float* __restrict__ chI, const float* __restrict__ chP,
    const float* __restrict__ wkv0,
    float* __restrict__ chS0, float* __restrict__ sfin)
{
    int tid = threadIdx.x;
    int blk = blockIdx.x;                       // 0..31
    int b = blk >> 4;
    int kr = (blk & 15) * 4 + (tid >> 6);       // k-row
    int v = tid & 63;
    float s = wkv0[(size_t)b * THD * THD + (size_t)kr * THD + v];
    for (int ch = 0; ch < TNCH; ++ch){
        size_t base = (size_t)(b * TNCH + ch);
        float P = chP[base * THD + kr];
        float I = chI[base * THD * THD + (size_t)kr * THD + v];
        chS0[base * THD * THD + (size_t)kr * THD + v] = s;
        s = s * P + I;
    }
    sfin[(size_t)b * THD * THD + (size_t)kr * THD + v] = s;
}

// ---------------- scan pass C: 128 chunks of 32 steps ----------------
// grid 256, 256 thr
__global__ __launch_bounds__(256) void k_scanC(
    const float* __restrict__ rbuf, const float* __restrict__ kbuf,
    const float* __restrict__ vbuf, const float* __restrict__ logwb,
    const float* __restrict__ chS0, const float* __restrict__ faaaa,
    float* __restrict__ obuf)
{
    __shared__ float rl[32][65], kl[32][65], vl[32][65], ewl[32][65];
    __shared__ float part[4][64];
    __shared__ float ruk[32];
    __shared__ float ul[64];
    int tid = threadIdx.x;
    int b = blockIdx.x >> 7, ch = blockIdx.x & 127;
    int w = tid >> 6, v = tid & 63, kb = w * 16;
    if (tid < 64) ul[tid] = faaaa[tid];
    float s[16];
    {
        size_t base = ((size_t)(b * TNCH + ch)) * THD * THD;
#pragma unroll
        for (int i = 0; i < 16; ++i) s[i] = chS0[base + (size_t)(kb + i) * THD + v];
    }
    int t0 = b * TT + ch * 32;
    for (int i = 0; i < 8; ++i){
        int flat = i * 256 + tid;
        int tt = flat >> 6, j = flat & 63;
        size_t g = (size_t)(t0 + tt) * THD + j;
        rl[tt][j] = rbuf[g];
        kl[tt][j] = kbuf[g];
        vl[tt][j] = vbuf[g];
        ewl[tt][j] = expf(logwb[g]);
    }
    __syncthreads();
    if (tid < 32){
        float a = 0.f;
#pragma unroll 8
        for (int k = 0; k < 64; ++k) a += rl[tid][k] * ul[k] * kl[tid][k];
        ruk[tid] = a;
    }
    __syncthreads();
    for (int t = 0; t < 32; ++t){
        float vv = vl[t][v];
        float pp = 0.f;
#pragma unroll
        for (int i = 0; i < 16; ++i) pp += rl[t][kb + i] * s[i];
        part[w][v] = pp;
        __syncthreads();
        if (w == 0){
            float o = part[0][v] + part[1][v] + part[2][v] + part[3][v] + ruk[t] * vv;
            obuf[(size_t)(t0 + t) * THD + v] = o;
        }
#pragma unroll
        for (int i = 0; i < 16; ++i){
            float e = ewl[t][kb + i], kk = kl[t][kb + i];
            s[i] = s[i] * e + kk * vv;
        }
        __syncthreads();
    }
}

// ---------------- out MFMA: out = (o*silu(g)) @ Wo ----------------
// grid (128 M, 16 N-tiles of 128), 256 thr
__global__ __launch_bounds__(256) void k_out_mfma(
    const float* __restrict__ obuf, const float* __restrict__ gpre,
    const unsigned short* __restrict__ Wob, float* __restrict__ outp)
{
    __shared__ unsigned short As[64 * 72];    // [m][k=64] pad 72
    __shared__ unsigned short Bs[128 * 72];   // [n][k=64] pad 72
    int tid = threadIdx.x;
    int wv = tid >> 6, ln = tid & 63;
    int lm = ln & 15, lq = ln >> 4;
    int n0 = blockIdx.x * 64, c0 = blockIdx.y * 128;

    for (int i = tid; i < 1024; i += 256){   // 64 rows x 16 f4-groups
        int r = i >> 4, g = i & 15;
        size_t base = (size_t)(n0 + r) * THD + g * 4;
        float4 ov = *(const float4*)(obuf + base);
        float4 gv = *(const float4*)(gpre + base);
        ushort4 u;
        u.x = f2us(ov.x * (gv.x / (1.f + expf(-gv.x))));
        u.y = f2us(ov.y * (gv.y / (1.f + expf(-gv.y))));
        u.z = f2us(ov.z * (gv.z / (1.f + expf(-gv.z))));
        u.w = f2us(ov.w * (gv.w / (1.f + expf(-gv.w))));
        *(ushort4*)(As + r * 72 + g * 4) = u;
    }
    for (int i = tid; i < 1024; i += 256){   // 64 k x 16 groups(of 8 n)
        int k = i >> 4, ng = i & 15;
        uint4 w4 = *(const uint4*)(Wob + (size_t)k * TC + c0 + ng * 8);
        const unsigned short* ww = (const unsigned short*)&w4;
#pragma unroll
        for (int j = 0; j < 8; ++j) Bs[(ng * 8 + j) * 72 + k] = ww[j];
    }
    __syncthreads();

    f32x4 zero = {0.f, 0.f, 0.f, 0.f};
    f32x4 acc[8];
#pragma unroll
    for (int i = 0; i < 8; ++i) acc[i] = zero;
#pragma unroll
    for (int ks = 0; ks < 2; ++ks){
        bf16x8 af = *(const bf16x8*)(As + (wv * 16 + lm) * 72 + ks * 32 + lq * 8);
#pragma unroll
        for (int nt = 0; nt < 8; ++nt){
            bf16x8 bf_ = *(const bf16x8*)(Bs + (nt * 16 + lm) * 72 + ks * 32 + lq * 8);
            acc[nt] = __builtin_amdgcn_mfma_f32_16x16x32_bf16(af, bf_, acc[nt], 0, 0, 0);
        }
    }
#pragma unroll
    for (int nt = 0; nt < 8; ++nt)
#pragma unroll
        for (int i = 0; i < 4; ++i){
            int n = n0 + wv * 16 + lq * 4 + i;
            outp[(size_t)n * TC + c0 + nt * 16 + lm] = acc[nt][i];
        }
}

extern "C" void kernel_launch(void* const* d_in, const int* in_sizes, int n_in,
                              void* d_out, int out_size, void* d_ws, size_t ws_size,
                              hipStream_t stream)
{
    const float* hs    = (const float*)d_in[0];
    const float* shift = (const float*)d_in[1];
    const float* wkv0  = (const float*)d_in[2];
    const float* maax  = (const float*)d_in[3];
    const float* maaw  = (const float*)d_in[4];
    const float* maak  = (const float*)d_in[5];
    const float* maav  = (const float*)d_in[6];
    const float* maar  = (const float*)d_in[7];
    const float* maag  = (const float*)d_in[8];
    const float* w1    = (const float*)d_in[9];
    const float* w2    = (const float*)d_in[10];
    const float* tdec  = (const float*)d_in[11];
    const float* dw1   = (const float*)d_in[12];
    const float* dw2   = (const float*)d_in[13];
    const float* faaaa = (const float*)d_in[14];
    const float* Wr    = (const float*)d_in[15];
    const float* Wk    = (const float*)d_in[16];
    const float* Wv    = (const float*)d_in[17];
    const float* Wg    = (const float*)d_in[18];
    const float* Wo    = (const float*)d_in[19];

    if (ws_size < 186384384ULL) return;

    char* ws = (char*)d_ws;
    unsigned short* w1T  = (unsigned short*)(ws + 0);             // 160x2048 bf16 (transposed)
    unsigned short* w2T  = (unsigned short*)(ws + 655360);        // 5x2048x32 bf16 (transposed)
    unsigned short* Wblk = (unsigned short*)(ws + 1310720);       // 5x32x64x64 bf16 (K-blocked)
    unsigned short* Wob  = (unsigned short*)(ws + 2621440);       // 64x2048 bf16
    unsigned short* G1b  = (unsigned short*)(ws + 2883584);       // 8192x160 bf16
    char*           x5r  = ws + 8126464;                          // 168 MB region
    unsigned short* X5   = (unsigned short*)x5r;                  // 5 planes bf16
    float*          Gpart= (float*)x5r;                           // alias (pre-mix lifetime, 8 slices)
    float*          logwb= (float*)(x5r + 0);                     // alias (post-proj lifetime)
    float*          obuf = (float*)(x5r + 2097152);
    float*          chI  = (float*)(x5r + 4194304);               // 8 MB (128 chunks)
    float*          chS0 = (float*)(x5r + 12582912);              // 8 MB
    float*          chP  = (float*)(x5r + 20971520);              // 64 KB
    float*          rbuf = (float*)(ws + 175898624);
    float*          kbuf = (float*)(ws + 177995776);
    float*          vbuf = (float*)(ws + 180092928);
    float*          gpre = (float*)(ws + 182190080);
    float*          dpre = (float*)(ws + 184287232);

    float* outp = (float*)d_out;
    float* lxp  = outp + (size_t)TM * TC;
    float* sfin = lxp + (size_t)TB * TC;

    k_w1t   <<<32, 256, 0, stream>>>(w1, w1T);
    k_cvt   <<<128, 256, 0, stream>>>(Wo, Wob, 32768);
    k_w2t   <<<dim3(32, 5), 256, 0, stream>>>(w2, w2T);
    k_cvt5t <<<dim3(32, 5), 256, 0, stream>>>(Wr, Wk, Wv, Wg, dw1, Wblk);
    k_lx    <<<16, 256, 0, stream>>>(hs, lxp);

    k_gemm1_mfma <<<dim3(128, 8), 256, 0, stream>>>(hs, shift, maax, w1T, Gpart);
    k_g1tanhb    <<<1280, 256, 0, stream>>>(Gpart, G1b);
    k_mix_mfma   <<<dim3(128, 32), 256, 0, stream>>>(hs, shift, G1b, w2T,
                                                     maaw, maak, maav, maar, maag, X5);
    k_proj_mfma  <<<dim3(128, 5), 256, 0, stream>>>(X5, Wblk, rbuf, kbuf, vbuf, gpre, dpre);
    k_wdecay     <<<512, 256, 0, stream>>>(dpre, dw2, tdec, logwb);
    k_scanA      <<<256, 256, 0, stream>>>(kbuf, vbuf, logwb, chI, chP);
    k_scanB      <<<32, 256, 0, stream>>>(chI, chP, wkv0, chS0, sfin);
    k_scanC      <<<256, 256, 0, stream>>>(rbuf, kbuf, vbuf, logwb, chS0, faaaa, obuf);
    k_out_mfma   <<<dim3(128, 16), 256, 0, stream>>>(obuf, gpre, Wob, outp);
}